// Round 24
// baseline (24.139 us; speedup 1.0000x reference)
//
#include <hip/hip_runtime.h>
#include <hip/hip_bf16.h>

// Problem constants (fixed by setup_inputs)
#define NB 16          // molecules
#define NA 384         // atoms per molecule
#define NOFFS 27       // periodic image offsets
#define MAXP 400000
#define CUT 5.5f

// count pass: 1536 blocks x 256 thr, wave owns one i-row
#define TPBC 256
#define WPBC 4
#define BPMC (NA/WPBC)          // 96 count-blocks per molecule
#define NBLKC (NB*BPMC)         // 1536
// write pass: 768 blocks x 512 thr, wave owns one i-row
#define TPBW 512
#define WPBW 8
#define BPMW (NA/WPBW)          // 48 write-blocks per molecule
#define NBLKW (NB*BPMW)         // 768

#define NSTRM (NB*NOFFS)        // 432 (b,o) output streams
#define NPB (NSTRM*BPMC)        // 41472 per-(stream,count-block) partials
#define NWAVES (NB*NA)          // 6144 global i-rows
#define LCAP 128                // list slots per row (mean ~46 valid)

// ws layout (int32 indices)
#define WS_PB    0                        // PB[(b*27+o)*96 + blkc]
#define WS_WCNT  (NPB)                    // WCNT[bidc*108 + o*4 + wc]
#define WS_BMAX  (WS_WCNT + NBLKC*108)    // [1536] per-count-block max|offset|
#define WS_BTOT  (WS_BMAX + NBLKC)        // [1536] per-count-block total valid
#define WS_WTOT  (WS_BTOT + NBLKC)        // [6144] per-row valid count
#define WS_LIST  (WS_WTOT + NWAVES)       // [6144*128] packed candidate entries

// IEEE single ops, no FMA contraction (replicate XLA's plain mul/add chain)
__device__ __forceinline__ float f_add(float a, float b){ return __fadd_rn(a,b); }
__device__ __forceinline__ float f_sub(float a, float b){ return __fsub_rn(a,b); }
__device__ __forceinline__ float f_mul(float a, float b){ return __fmul_rn(a,b); }

// 3x3 inverse via adjugate (diagonal cell -> exact diag(1/18), exact 0 elsewhere)
__device__ __forceinline__ void make_inv(const float* cl, float* invc) {
  float a=cl[0], b=cl[1], c=cl[2], d=cl[3], e=cl[4], f=cl[5], g=cl[6], h=cl[7], i=cl[8];
  float A = f_sub(f_mul(e,i), f_mul(f,h));
  float B = f_sub(f_mul(f,g), f_mul(d,i));
  float C = f_sub(f_mul(d,h), f_mul(e,g));
  float det = f_add(f_add(f_mul(a,A), f_mul(b,B)), f_mul(c,C));
  invc[0] = __fdiv_rn(A, det);
  invc[1] = __fdiv_rn(f_sub(f_mul(c,h), f_mul(b,i)), det);
  invc[2] = __fdiv_rn(f_sub(f_mul(b,f), f_mul(c,e)), det);
  invc[3] = __fdiv_rn(B, det);
  invc[4] = __fdiv_rn(f_sub(f_mul(a,i), f_mul(c,g)), det);
  invc[5] = __fdiv_rn(f_sub(f_mul(c,d), f_mul(a,f)), det);
  invc[6] = __fdiv_rn(C, det);
  invc[7] = __fdiv_rn(f_sub(f_mul(b,g), f_mul(a,h)), det);
  invc[8] = __fdiv_rn(f_sub(f_mul(a,e), f_mul(b,d)), det);
}

// Wrap one atom: proj -> floor (wrap offset) -> frac -> wrapped coord.
// EXACT same FP chain as the reference (bit-identical regardless of caller).
__device__ __forceinline__ void wrap_one(
    float cx, float cy, float cz, const float* cl, const float* invc,
    float& wx, float& wy, float& wz, int& wox, int& woy, int& woz)
{
  float p0 = f_add(f_add(f_mul(cx, invc[0]), f_mul(cy, invc[3])), f_mul(cz, invc[6]));
  float p1 = f_add(f_add(f_mul(cx, invc[1]), f_mul(cy, invc[4])), f_mul(cz, invc[7]));
  float p2 = f_add(f_add(f_mul(cx, invc[2]), f_mul(cy, invc[5])), f_mul(cz, invc[8]));
  float fl0 = floorf(p0), fl1 = floorf(p1), fl2 = floorf(p2);
  wox = (int)fl0; woy = (int)fl1; woz = (int)fl2;
  float fr0 = f_sub(p0, fl0), fr1 = f_sub(p1, fl1), fr2 = f_sub(p2, fl2);
  wx = f_add(f_add(f_mul(fr0, cl[0]), f_mul(fr1, cl[3])), f_mul(fr2, cl[6]));
  wy = f_add(f_add(f_mul(fr0, cl[1]), f_mul(fr1, cl[4])), f_mul(fr2, cl[7]));
  wz = f_add(f_add(f_mul(fr0, cl[2]), f_mul(fr1, cl[5])), f_mul(fr2, cl[8]));
}

// Nearest-image select: k = rint(d0/L) in {-1,0,1}; P = -L*k exact; oi = -k.
#define SELECT_P(d0, negLd, invLd, P, oi) \
  { const float kk = __builtin_rintf(f_mul(d0, invLd)); \
    P = f_mul(kk, negLd); oi = -(int)kk; }

__global__ __launch_bounds__(TPBC) void count_k(
    const float* __restrict__ coords, const float* __restrict__ cell,
    int* __restrict__ ws)
{
  const int bid = blockIdx.x;
  const int b = bid / BPMC;
  const int blkm = bid % BPMC;
  __shared__ int cw[WPBC*27];
  __shared__ int wmax[WPBC], wtot4[WPBC];
  const int t = threadIdx.x;
  const int w = t >> 6, lane = t & 63;

  float clr[9], invc[9];
  #pragma unroll
  for (int q = 0; q < 9; ++q) clr[q] = cell[b*9 + q];
  make_inv(clr, invc);

  // each wave zeroes its OWN counters (wave-order visibility, no barrier)
  if (lane < 27) cw[w*27 + lane] = 0;

  // i-side: wave-uniform load + in-register wrap (bit-identical chain)
  const int i = blkm*WPBC + w;
  const float cix = coords[(b*NA + i)*3 + 0];
  const float ciy = coords[(b*NA + i)*3 + 1];
  const float ciz = coords[(b*NA + i)*3 + 2];
  float wxi, wyi, wzi; int woxi, woyi, wozi;
  wrap_one(cix, ciy, ciz, clr, invc, wxi, wyi, wzi, woxi, woyi, wozi);

  const float nLx = -clr[0], nLy = -clr[4], nLz = -clr[8];
  const float iLx = __frcp_rn(clr[0]), iLy = __frcp_rn(clr[4]), iLz = __frcp_rn(clr[8]);
  const int gwid = b*NA + i;
  const unsigned long long lower = (1ull << lane) - 1ull;
  const float3* __restrict__ c3 = (const float3*)(coords + b*NA*3);

  int mx = 0;
  int wbase = 0;
  #pragma unroll
  for (int jb = 0; jb < 6; ++jb) {
    const int j = jb*64 + lane;
    const float3 c = c3[j];
    float wxj, wyj, wzj; int woxj, woyj, wozj;
    wrap_one(c.x, c.y, c.z, clr, invc, wxj, wyj, wzj, woxj, woyj, wozj);
    const float d0x = f_sub(wxi, wxj);
    const float d0y = f_sub(wyi, wyj);
    const float d0z = f_sub(wzi, wzj);
    float Px, Py, Pz; int ox, oy, oz;
    SELECT_P(d0x, nLx, iLx, Px, ox);
    SELECT_P(d0y, nLy, iLy, Py, oy);
    SELECT_P(d0z, nLz, iLz, Pz, oz);
    const float dx = f_add(d0x, Px);
    const float dy = f_add(d0y, Py);
    const float dz = f_add(d0z, Pz);
    const float s = f_add(f_add(f_mul(dx,dx), f_mul(dy,dy)), f_mul(dz,dz));
    const float dist = __fsqrt_rn(s);
    const int oidx = 13 + 9*ox + 3*oy + oz;
    const bool valid = (dist < CUT) && (oidx != 13 || i != j);
    const unsigned long long vm = __ballot(valid);
    if (valid) {
      atomicAdd(&cw[w*27 + oidx], 1);
      const int o0 = ox - (woxi - woxj);
      const int o1 = oy - (woyi - woyj);
      const int o2 = oz - (wozi - wozj);
      int am = abs(o0); am = max(am, abs(o1)); am = max(am, abs(o2));
      mx = max(mx, am);
      const int pos = wbase + __popcll(vm & lower);
      if (pos < LCAP) {
        const int ent = j | (oidx << 9) | ((o0+2) << 14) | ((o1+2) << 17) | ((o2+2) << 20);
        ws[WS_LIST + gwid*LCAP + pos] = ent;
      }
    }
    wbase += __popcll(vm);
  }
  #pragma unroll
  for (int d = 32; d > 0; d >>= 1) mx = max(mx, __shfl_down(mx, d));
  if (lane == 0) {
    wmax[w] = mx;
    wtot4[w] = wbase;
    ws[WS_WTOT + gwid] = (wbase < LCAP) ? wbase : LCAP;
  }
  __syncthreads();   // the ONLY block barrier: cross-wave epilogue below
  // per-(o,wc) counts:  WCNT[bid*108 + o*4 + wc]
  if (t < WPBC*27) ws[WS_WCNT + bid*108 + t] = cw[(t & 3)*27 + (t >> 2)];
  // per-(b,o) block partial: PB[(b*27+o)*96 + blkm]
  if (t < 27) {
    int s = 0;
    #pragma unroll
    for (int q = 0; q < WPBC; ++q) s += cw[q*27 + t];
    ws[WS_PB + (b*27 + t)*BPMC + blkm] = s;
  }
  if (t == 0) {
    int m = 0, tt = 0;
    #pragma unroll
    for (int q = 0; q < WPBC; ++q) { m = max(m, wmax[q]); tt += wtot4[q]; }
    ws[WS_BMAX + bid] = m;
    ws[WS_BTOT + bid] = tt;
  }
}

__global__ __launch_bounds__(TPBW) void write_k(
    const float* __restrict__ coords, const float* __restrict__ cell,
    const int* __restrict__ ira, const int* __restrict__ ws,
    float* __restrict__ out)
{
  const int bid = blockIdx.x;
  const int b = bid / BPMW;
  const int blkw = bid % BPMW;
  __shared__ int cur[WPBW*27];   // cursors [w*27+o]
  __shared__ int wl[27*WPBW];    // per-(o,w) counts [o*8+w]
  __shared__ int sst[27];        // global stream starts for own b
  __shared__ int sbl[27];        // own-stream prefix over count-blocks < 2*blkw
  __shared__ int ss27[27];       // own-molecule stream sums
  __shared__ int mtot[NB];       // per-molecule totals
  __shared__ int wmax8[8];
  __shared__ int scal[2];        // total, mi
  const int t = threadIdx.x;
  const int w = t >> 6, lane = t & 63;

  float clr[9];
  #pragma unroll
  for (int q = 0; q < 9; ++q) clr[q] = cell[b*9 + q];

  // wl[o*8+w8] = WCNT[(b*96 + blkw*2 + (w8>>2))*108 + o*4 + (w8&3)]
  if (t < 216) {
    const int o = t >> 3, w8 = t & 7;
    const int bidc = b*BPMC + blkw*2 + (w8 >> 2);
    wl[o*8 + w8] = ws[WS_WCNT + bidc*108 + o*4 + (w8 & 3)];
  }
  // preload this wave's candidate list (2 rounds of 64)
  const int gwid = b*NA + blkw*WPBW + w;
  const int wtot = ws[WS_WTOT + gwid];
  const int e0 = (lane < wtot) ? ws[WS_LIST + gwid*LCAP + lane] : 0;
  const int e1 = (64 + lane < wtot) ? ws[WS_LIST + gwid*LCAP + 64 + lane] : 0;
  // i-side data (wave-uniform; coords/ira are L2-resident)
  const int i = blkw*WPBW + w;
  const float cxi = coords[(b*NA + i)*3 + 0];
  const float cyi = coords[(b*NA + i)*3 + 1];
  const float czi = coords[(b*NA + i)*3 + 2];
  const int pfi = ira[b*NA + i];
  // (a) own stream sums + sbl, direct from global PB (16-lane group per stream)
  if (t < 432) {
    const int o = t >> 4, qq = t & 15;
    const int base = (b*27 + o)*BPMC;
    const int limit = 2*blkw;
    int sfull = 0, spart = 0;
    #pragma unroll
    for (int g = 0; g < 6; ++g) {
      const int q = qq + g*16;
      const int v = ws[WS_PB + base + q];
      sfull += v;
      if (q < limit) spart += v;
    }
    #pragma unroll
    for (int d = 1; d < 16; d <<= 1) { sfull += __shfl_xor(sfull, d); spart += __shfl_xor(spart, d); }
    if (qq == 0) { ss27[o] = sfull; sbl[o] = spart; }
  }
  // (b) per-molecule totals from BTOT: 32-lane group per molecule
  {
    const int g = t >> 5, l = t & 31;       // g in [0,16)
    int v = 0;
    #pragma unroll
    for (int k = 0; k < 3; ++k) v += ws[WS_BTOT + g*BPMC + l + k*32];
    #pragma unroll
    for (int d = 1; d < 32; d <<= 1) v += __shfl_xor(v, d);
    if (l == 0) mtot[g] = v;
  }
  // (d) mi: reduce 1536 block maxes, 3 strided per thread
  {
    int m = 0;
    #pragma unroll
    for (int g = 0; g < NBLKC/TPBW; ++g) m = max(m, ws[WS_BMAX + g*TPBW + t]);
    #pragma unroll
    for (int d = 32; d > 0; d >>= 1) m = max(m, __shfl_down(m, d));
    if (lane == 0) wmax8[w] = m;
  }
  __syncthreads();
  if (t == 0) {
    // serial (43 adds): molecule starts, grand total, own stream starts, mi
    int run = 0, msb = 0;
    #pragma unroll
    for (int m = 0; m < NB; ++m) { if (m == b) msb = run; run += mtot[m]; }
    scal[0] = run;
    int r2 = msb;
    #pragma unroll
    for (int o = 0; o < 27; ++o) { sst[o] = r2; r2 += ss27[o]; }
    int mm = 0;
    #pragma unroll
    for (int q = 0; q < 8; ++q) mm = max(mm, wmax8[q]);
    scal[1] = mm;
  }
  __syncthreads();
  const int mi = scal[1];
  const int nf = 2*mi + 1;
  int total = scal[0]; if (total > MAXP) total = MAXP;
  // cursors: stream start + block prefix + wave prefix within write-block
  if (t < 216) {
    const int o = t >> 3, w8 = t & 7;
    int s = sst[o] + sbl[o];
    for (int q = 0; q < w8; ++q) s += wl[o*8 + q];
    cur[w8*27 + o] = s;
  }
  __syncthreads();

  // ---- ordered write: replay the cached list (2 rounds); j-side gathered
  // directly from L2-resident coords/ira (no LDS staging) ----
  const unsigned long long lower = (1ull << lane) - 1ull;
  #pragma unroll
  for (int r = 0; r < 2; ++r) {
    const int e = r ? e1 : e0;
    const bool active = (r*64 + lane) < wtot;
    const int oidx = (e >> 9) & 31;
    unsigned long long same = __ballot(active);
    #pragma unroll
    for (int k = 0; k < 5; ++k) {
      const unsigned long long bk = __ballot((oidx >> k) & 1);
      same &= ((oidx >> k) & 1) ? bk : ~bk;
    }
    if (active) {
      const int rank = __popcll(same & lower);
      const int bse = cur[w*27 + oidx];         // broadcast read per group
      if ((same & lower) == 0ull)               // leader advances cursor
        cur[w*27 + oidx] = bse + __popcll(same);
      const int p = bse + rank;
      if (p < MAXP) {
        const int j = e & 511;
        const float cxj = coords[(b*NA + j)*3 + 0];
        const float cyj = coords[(b*NA + j)*3 + 1];
        const float czj = coords[(b*NA + j)*3 + 2];
        const int o0 = ((e >> 14) & 7) - 2;
        const int o1 = ((e >> 17) & 7) - 2;
        const int o2 = ((e >> 20) & 7) - 2;
        const float g0 = (float)o0, g1 = (float)o1, g2 = (float)o2;
        const float qx = f_add(f_add(f_mul(g0, clr[0]), f_mul(g1, clr[3])), f_mul(g2, clr[6]));
        const float qy = f_add(f_add(f_mul(g0, clr[1]), f_mul(g1, clr[4])), f_mul(g2, clr[7]));
        const float qz = f_add(f_add(f_mul(g0, clr[2]), f_mul(g1, clr[5])), f_mul(g2, clr[8]));
        const float ax = f_add(f_sub(cxi, cxj), qx);
        const float ay = f_add(f_sub(cyi, cyj), qy);
        const float az = f_add(f_sub(czi, czj), qz);
        const float s2 = f_add(f_add(f_mul(ax,ax), f_mul(ay,ay)), f_mul(az,az));
        const float dd = __fsqrt_rn(s2);
        out[p]          = dd;
        out[MAXP + p]   = (float)pfi;
        out[2*MAXP + p] = (float)ira[b*NA + j];
        out[3*MAXP + 3*p + 0] = ax;
        out[3*MAXP + 3*p + 1] = ay;
        out[3*MAXP + 3*p + 2] = az;
        out[6*MAXP + 3*p + 0] = g0;
        out[6*MAXP + 3*p + 1] = g1;
        out[6*MAXP + 3*p + 2] = g2;
        out[9*MAXP + p] = (float)((o2+mi) + nf*((o1+mi) + nf*(o0+mi)));
      }
    }
  }

  // Tail fill: slots [total, MAXP) -> zeros except offset_index pad value.
  const float oidx_pad = (float)(mi*(1 + nf + nf*nf));
  const int gtid = bid*TPBW + t;
  for (int p = total + gtid; p < MAXP; p += NBLKW*TPBW) {
    out[p] = 0.0f;
    out[MAXP + p] = 0.0f;
    out[2*MAXP + p] = 0.0f;
    out[3*MAXP + 3*p + 0] = 0.0f;
    out[3*MAXP + 3*p + 1] = 0.0f;
    out[3*MAXP + 3*p + 2] = 0.0f;
    out[6*MAXP + 3*p + 0] = 0.0f;
    out[6*MAXP + 3*p + 1] = 0.0f;
    out[6*MAXP + 3*p + 2] = 0.0f;
    out[9*MAXP + p] = oidx_pad;
  }
}

extern "C" void kernel_launch(void* const* d_in, const int* in_sizes, int n_in,
                              void* d_out, int out_size, void* d_ws, size_t ws_size,
                              hipStream_t stream) {
  const float* coords = (const float*)d_in[0];   // [16,384,3] f32
  const int*   ira    = (const int*)d_in[3];     // inv_real_atoms [6144]
  const float* cell   = (const float*)d_in[4];   // [16,3,3] f32
  int* ws = (int*)d_ws;
  float* out = (float*)d_out;

  count_k<<<NBLKC, TPBC, 0, stream>>>(coords, cell, ws);
  write_k<<<NBLKW, TPBW, 0, stream>>>(coords, cell, ira, ws, out);
}

// Round 25
// 22.828 us; speedup vs baseline: 1.0575x; 1.0575x over previous
//
#include <hip/hip_runtime.h>
#include <hip/hip_bf16.h>

// Problem constants (fixed by setup_inputs)
#define NB 16          // molecules
#define NA 384         // atoms per molecule
#define NOFFS 27       // periodic image offsets
#define MAXP 400000
#define CUT 5.5f

// count pass: 1536 blocks x 256 thr, wave owns one i-row
#define TPBC 256
#define WPBC 4
#define BPMC (NA/WPBC)          // 96 count-blocks per molecule
#define NBLKC (NB*BPMC)         // 1536
// write pass: 768 blocks x 512 thr, wave owns one i-row
#define TPBW 512
#define WPBW 8
#define BPMW (NA/WPBW)          // 48 write-blocks per molecule
#define NBLKW (NB*BPMW)         // 768

#define NSTRM (NB*NOFFS)        // 432 (b,o) output streams
#define NPB (NSTRM*BPMC)        // 41472 per-(stream,count-block) partials
#define NWAVES (NB*NA)          // 6144 global i-rows
#define LCAP 128                // list slots per row (mean ~46 valid)

// ws layout (int32 indices)
#define WS_PB    0                        // PB[(b*27+o)*96 + blkc]
#define WS_WCNT  (NPB)                    // WCNT[bidc*108 + o*4 + wc]
#define WS_BMAX  (WS_WCNT + NBLKC*108)    // [1536] per-count-block max|offset|
#define WS_BTOT  (WS_BMAX + NBLKC)        // [1536] per-count-block total valid
#define WS_WTOT  (WS_BTOT + NBLKC)        // [6144] per-row valid count
#define WS_LIST  (WS_WTOT + NWAVES)       // [6144*128] packed candidate entries

// IEEE single ops, no FMA contraction (replicate XLA's plain mul/add chain)
__device__ __forceinline__ float f_add(float a, float b){ return __fadd_rn(a,b); }
__device__ __forceinline__ float f_sub(float a, float b){ return __fsub_rn(a,b); }
__device__ __forceinline__ float f_mul(float a, float b){ return __fmul_rn(a,b); }

// 3x3 inverse via adjugate (diagonal cell -> exact diag(1/18), exact 0 elsewhere)
__device__ __forceinline__ void make_inv(const float* cl, float* invc) {
  float a=cl[0], b=cl[1], c=cl[2], d=cl[3], e=cl[4], f=cl[5], g=cl[6], h=cl[7], i=cl[8];
  float A = f_sub(f_mul(e,i), f_mul(f,h));
  float B = f_sub(f_mul(f,g), f_mul(d,i));
  float C = f_sub(f_mul(d,h), f_mul(e,g));
  float det = f_add(f_add(f_mul(a,A), f_mul(b,B)), f_mul(c,C));
  invc[0] = __fdiv_rn(A, det);
  invc[1] = __fdiv_rn(f_sub(f_mul(c,h), f_mul(b,i)), det);
  invc[2] = __fdiv_rn(f_sub(f_mul(b,f), f_mul(c,e)), det);
  invc[3] = __fdiv_rn(B, det);
  invc[4] = __fdiv_rn(f_sub(f_mul(a,i), f_mul(c,g)), det);
  invc[5] = __fdiv_rn(f_sub(f_mul(c,d), f_mul(a,f)), det);
  invc[6] = __fdiv_rn(C, det);
  invc[7] = __fdiv_rn(f_sub(f_mul(b,g), f_mul(a,h)), det);
  invc[8] = __fdiv_rn(f_sub(f_mul(a,e), f_mul(b,d)), det);
}

// Nearest-image select: k = rint(d0/L) in {-1,0,1}; P = -L*k exact; oi = -k.
#define SELECT_P(d0, negLd, invLd, P, oi) \
  { const float kk = __builtin_rintf(f_mul(d0, invLd)); \
    P = f_mul(kk, negLd); oi = -(int)kk; }

__global__ __launch_bounds__(TPBC) void count_k(
    const float* __restrict__ coords, const float* __restrict__ cell,
    int* __restrict__ ws)
{
  const int bid = blockIdx.x;
  const int b = bid / BPMC;
  const int blkm = bid % BPMC;
  __shared__ float wx[NA], wy[NA], wz[NA];
  __shared__ int wox[NA], woy[NA], woz[NA];
  __shared__ int cw[WPBC*27];
  __shared__ int wmax[WPBC], wtot4[WPBC];
  const int t = threadIdx.x;
  const int w = t >> 6, lane = t & 63;

  float clr[9], invc[9];
  #pragma unroll
  for (int q = 0; q < 9; ++q) clr[q] = cell[b*9 + q];
  make_inv(clr, invc);

  if (t < WPBC*27) cw[t] = 0;
  {
    const float3* __restrict__ c3 = (const float3*)(coords + b*NA*3);
    for (int i = t; i < NA; i += TPBC) {
      const float3 c = c3[i];
      float p0 = f_add(f_add(f_mul(c.x, invc[0]), f_mul(c.y, invc[3])), f_mul(c.z, invc[6]));
      float p1 = f_add(f_add(f_mul(c.x, invc[1]), f_mul(c.y, invc[4])), f_mul(c.z, invc[7]));
      float p2 = f_add(f_add(f_mul(c.x, invc[2]), f_mul(c.y, invc[5])), f_mul(c.z, invc[8]));
      float fl0 = floorf(p0), fl1 = floorf(p1), fl2 = floorf(p2);
      wox[i] = (int)fl0; woy[i] = (int)fl1; woz[i] = (int)fl2;
      float fr0 = f_sub(p0, fl0), fr1 = f_sub(p1, fl1), fr2 = f_sub(p2, fl2);
      wx[i] = f_add(f_add(f_mul(fr0, clr[0]), f_mul(fr1, clr[3])), f_mul(fr2, clr[6]));
      wy[i] = f_add(f_add(f_mul(fr0, clr[1]), f_mul(fr1, clr[4])), f_mul(fr2, clr[7]));
      wz[i] = f_add(f_add(f_mul(fr0, clr[2]), f_mul(fr1, clr[5])), f_mul(fr2, clr[8]));
    }
  }
  __syncthreads();

  const float nLx = -clr[0], nLy = -clr[4], nLz = -clr[8];
  const float iLx = __frcp_rn(clr[0]), iLy = __frcp_rn(clr[4]), iLz = __frcp_rn(clr[8]);
  const int i = blkm*WPBC + w;
  const float wxi = wx[i], wyi = wy[i], wzi = wz[i];
  const int woxi = wox[i], woyi = woy[i], wozi = woz[i];
  const int gwid = b*NA + i;
  const unsigned long long lower = (1ull << lane) - 1ull;

  int mx = 0;
  int wbase = 0;
  #pragma unroll
  for (int jb = 0; jb < 6; ++jb) {
    const int j = jb*64 + lane;
    const float d0x = f_sub(wxi, wx[j]);
    const float d0y = f_sub(wyi, wy[j]);
    const float d0z = f_sub(wzi, wz[j]);
    float Px, Py, Pz; int ox, oy, oz;
    SELECT_P(d0x, nLx, iLx, Px, ox);
    SELECT_P(d0y, nLy, iLy, Py, oy);
    SELECT_P(d0z, nLz, iLz, Pz, oz);
    const float dx = f_add(d0x, Px);
    const float dy = f_add(d0y, Py);
    const float dz = f_add(d0z, Pz);
    const float s = f_add(f_add(f_mul(dx,dx), f_mul(dy,dy)), f_mul(dz,dz));
    const float dist = __fsqrt_rn(s);
    const int oidx = 13 + 9*ox + 3*oy + oz;
    const bool valid = (dist < CUT) && (oidx != 13 || i != j);
    const unsigned long long vm = __ballot(valid);
    if (valid) {
      atomicAdd(&cw[w*27 + oidx], 1);
      const int o0 = ox - (woxi - wox[j]);
      const int o1 = oy - (woyi - woy[j]);
      const int o2 = oz - (wozi - woz[j]);
      int am = abs(o0); am = max(am, abs(o1)); am = max(am, abs(o2));
      mx = max(mx, am);
      const int pos = wbase + __popcll(vm & lower);
      if (pos < LCAP) {
        const int ent = j | (oidx << 9) | ((o0+2) << 14) | ((o1+2) << 17) | ((o2+2) << 20);
        ws[WS_LIST + gwid*LCAP + pos] = ent;
      }
    }
    wbase += __popcll(vm);
  }
  #pragma unroll
  for (int d = 32; d > 0; d >>= 1) mx = max(mx, __shfl_down(mx, d));
  if (lane == 0) {
    wmax[w] = mx;
    wtot4[w] = wbase;
    ws[WS_WTOT + gwid] = (wbase < LCAP) ? wbase : LCAP;
  }
  __syncthreads();
  // per-(o,wc) counts:  WCNT[bid*108 + o*4 + wc]
  if (t < WPBC*27) ws[WS_WCNT + bid*108 + t] = cw[(t & 3)*27 + (t >> 2)];
  // per-(b,o) block partial: PB[(b*27+o)*96 + blkm]
  if (t < 27) {
    int s = 0;
    #pragma unroll
    for (int q = 0; q < WPBC; ++q) s += cw[q*27 + t];
    ws[WS_PB + (b*27 + t)*BPMC + blkm] = s;
  }
  if (t == 0) {
    int m = 0, tt = 0;
    #pragma unroll
    for (int q = 0; q < WPBC; ++q) { m = max(m, wmax[q]); tt += wtot4[q]; }
    ws[WS_BMAX + bid] = m;
    ws[WS_BTOT + bid] = tt;
  }
}

__global__ __launch_bounds__(TPBW) void write_k(
    const float* __restrict__ coords, const float* __restrict__ cell,
    const int* __restrict__ ira, const int* __restrict__ ws,
    float* __restrict__ out)
{
  const int bid = blockIdx.x;
  const int b = bid / BPMW;
  const int blkw = bid % BPMW;
  __shared__ int cur[WPBW*27];   // cursors [w*27+o]
  __shared__ int wl[27*WPBW];    // per-(o,w) counts [o*8+w]
  __shared__ int sst[27];        // global stream starts for own b
  __shared__ int sbl[27];        // own-stream prefix over count-blocks < 2*blkw
  __shared__ int ss27[27];       // own-molecule stream sums
  __shared__ int mtot[NB];       // per-molecule totals
  __shared__ int wmax8[8];
  __shared__ int scal[2];        // total, mi
  const int t = threadIdx.x;
  const int w = t >> 6, lane = t & 63;

  float clr[9];
  #pragma unroll
  for (int q = 0; q < 9; ++q) clr[q] = cell[b*9 + q];

  // wl[o*8+w8] = WCNT[(b*96 + blkw*2 + (w8>>2))*108 + o*4 + (w8&3)]
  if (t < 216) {
    const int o = t >> 3, w8 = t & 7;
    const int bidc = b*BPMC + blkw*2 + (w8 >> 2);
    wl[o*8 + w8] = ws[WS_WCNT + bidc*108 + o*4 + (w8 & 3)];
  }
  // preload this wave's candidate list (2 rounds of 64)
  const int gwid = b*NA + blkw*WPBW + w;
  const int wtot = ws[WS_WTOT + gwid];
  const int e0 = (lane < wtot) ? ws[WS_LIST + gwid*LCAP + lane] : 0;
  const int e1 = (64 + lane < wtot) ? ws[WS_LIST + gwid*LCAP + 64 + lane] : 0;
  // i-side data (wave-uniform; coords/ira are L2-resident)
  const int i = blkw*WPBW + w;
  const float cxi = coords[(b*NA + i)*3 + 0];
  const float cyi = coords[(b*NA + i)*3 + 1];
  const float czi = coords[(b*NA + i)*3 + 2];
  const int pfi = ira[b*NA + i];
  // (a) own stream sums + sbl, direct from global PB (16-lane group per stream)
  if (t < 432) {
    const int o = t >> 4, qq = t & 15;
    const int base = (b*27 + o)*BPMC;
    const int limit = 2*blkw;
    int sfull = 0, spart = 0;
    #pragma unroll
    for (int g = 0; g < 6; ++g) {
      const int q = qq + g*16;
      const int v = ws[WS_PB + base + q];
      sfull += v;
      if (q < limit) spart += v;
    }
    #pragma unroll
    for (int d = 1; d < 16; d <<= 1) { sfull += __shfl_xor(sfull, d); spart += __shfl_xor(spart, d); }
    if (qq == 0) { ss27[o] = sfull; sbl[o] = spart; }
  }
  // (b) per-molecule totals from BTOT: 32-lane group per molecule
  {
    const int g = t >> 5, l = t & 31;       // g in [0,16)
    int v = 0;
    #pragma unroll
    for (int k = 0; k < 3; ++k) v += ws[WS_BTOT + g*BPMC + l + k*32];
    #pragma unroll
    for (int d = 1; d < 32; d <<= 1) v += __shfl_xor(v, d);
    if (l == 0) mtot[g] = v;
  }
  // (d) mi: reduce 1536 block maxes, 3 strided per thread
  {
    int m = 0;
    #pragma unroll
    for (int g = 0; g < NBLKC/TPBW; ++g) m = max(m, ws[WS_BMAX + g*TPBW + t]);
    #pragma unroll
    for (int d = 32; d > 0; d >>= 1) m = max(m, __shfl_down(m, d));
    if (lane == 0) wmax8[w] = m;
  }
  __syncthreads();
  if (t == 0) {
    // serial (43 adds): molecule starts, grand total, own stream starts, mi
    int run = 0, msb = 0;
    #pragma unroll
    for (int m = 0; m < NB; ++m) { if (m == b) msb = run; run += mtot[m]; }
    scal[0] = run;
    int r2 = msb;
    #pragma unroll
    for (int o = 0; o < 27; ++o) { sst[o] = r2; r2 += ss27[o]; }
    int mm = 0;
    #pragma unroll
    for (int q = 0; q < 8; ++q) mm = max(mm, wmax8[q]);
    scal[1] = mm;
  }
  __syncthreads();
  const int mi = scal[1];
  const int nf = 2*mi + 1;
  int total = scal[0]; if (total > MAXP) total = MAXP;
  // cursors: stream start + block prefix + wave prefix within write-block
  if (t < 216) {
    const int o = t >> 3, w8 = t & 7;
    int s = sst[o] + sbl[o];
    for (int q = 0; q < w8; ++q) s += wl[o*8 + q];
    cur[w8*27 + o] = s;
  }
  __syncthreads();

  // ---- ordered write: replay the cached list (2 rounds); j-side gathered
  // directly from L2-resident coords/ira (no LDS staging) ----
  const unsigned long long lower = (1ull << lane) - 1ull;
  #pragma unroll
  for (int r = 0; r < 2; ++r) {
    const int e = r ? e1 : e0;
    const bool active = (r*64 + lane) < wtot;
    const int oidx = (e >> 9) & 31;
    unsigned long long same = __ballot(active);
    #pragma unroll
    for (int k = 0; k < 5; ++k) {
      const unsigned long long bk = __ballot((oidx >> k) & 1);
      same &= ((oidx >> k) & 1) ? bk : ~bk;
    }
    if (active) {
      const int rank = __popcll(same & lower);
      const int bse = cur[w*27 + oidx];         // broadcast read per group
      if ((same & lower) == 0ull)               // leader advances cursor
        cur[w*27 + oidx] = bse + __popcll(same);
      const int p = bse + rank;
      if (p < MAXP) {
        const int j = e & 511;
        const float cxj = coords[(b*NA + j)*3 + 0];
        const float cyj = coords[(b*NA + j)*3 + 1];
        const float czj = coords[(b*NA + j)*3 + 2];
        const int o0 = ((e >> 14) & 7) - 2;
        const int o1 = ((e >> 17) & 7) - 2;
        const int o2 = ((e >> 20) & 7) - 2;
        const float g0 = (float)o0, g1 = (float)o1, g2 = (float)o2;
        const float qx = f_add(f_add(f_mul(g0, clr[0]), f_mul(g1, clr[3])), f_mul(g2, clr[6]));
        const float qy = f_add(f_add(f_mul(g0, clr[1]), f_mul(g1, clr[4])), f_mul(g2, clr[7]));
        const float qz = f_add(f_add(f_mul(g0, clr[2]), f_mul(g1, clr[5])), f_mul(g2, clr[8]));
        const float ax = f_add(f_sub(cxi, cxj), qx);
        const float ay = f_add(f_sub(cyi, cyj), qy);
        const float az = f_add(f_sub(czi, czj), qz);
        const float s2 = f_add(f_add(f_mul(ax,ax), f_mul(ay,ay)), f_mul(az,az));
        const float dd = __fsqrt_rn(s2);
        out[p]          = dd;
        out[MAXP + p]   = (float)pfi;
        out[2*MAXP + p] = (float)ira[b*NA + j];
        out[3*MAXP + 3*p + 0] = ax;
        out[3*MAXP + 3*p + 1] = ay;
        out[3*MAXP + 3*p + 2] = az;
        out[6*MAXP + 3*p + 0] = g0;
        out[6*MAXP + 3*p + 1] = g1;
        out[6*MAXP + 3*p + 2] = g2;
        out[9*MAXP + p] = (float)((o2+mi) + nf*((o1+mi) + nf*(o0+mi)));
      }
    }
  }

  // Tail fill: slots [total, MAXP) -> zeros except offset_index pad value.
  const float oidx_pad = (float)(mi*(1 + nf + nf*nf));
  const int gtid = bid*TPBW + t;
  for (int p = total + gtid; p < MAXP; p += NBLKW*TPBW) {
    out[p] = 0.0f;
    out[MAXP + p] = 0.0f;
    out[2*MAXP + p] = 0.0f;
    out[3*MAXP + 3*p + 0] = 0.0f;
    out[3*MAXP + 3*p + 1] = 0.0f;
    out[3*MAXP + 3*p + 2] = 0.0f;
    out[6*MAXP + 3*p + 0] = 0.0f;
    out[6*MAXP + 3*p + 1] = 0.0f;
    out[6*MAXP + 3*p + 2] = 0.0f;
    out[9*MAXP + p] = oidx_pad;
  }
}

extern "C" void kernel_launch(void* const* d_in, const int* in_sizes, int n_in,
                              void* d_out, int out_size, void* d_ws, size_t ws_size,
                              hipStream_t stream) {
  const float* coords = (const float*)d_in[0];   // [16,384,3] f32
  const int*   ira    = (const int*)d_in[3];     // inv_real_atoms [6144]
  const float* cell   = (const float*)d_in[4];   // [16,3,3] f32
  int* ws = (int*)d_ws;
  float* out = (float*)d_out;

  count_k<<<NBLKC, TPBC, 0, stream>>>(coords, cell, ws);
  write_k<<<NBLKW, TPBW, 0, stream>>>(coords, cell, ira, ws, out);
}